// Round 1
// baseline (372.946 us; speedup 1.0000x reference)
//
#include <hip/hip_runtime.h>
#include <cstdint>
#include <cstddef>

typedef unsigned int u32;

// ---------------------------------------------------------------------------
// GCN 2-layer forward, pull-based aggregation via CSR-by-dst built on device.
//   deg/norms -> CSR(dst) -> h=(x@W1)*nsrc -> agg1(relu(.*ndst+b1)*nsrc)
//   -> h2=out1s@W2 -> agg2(.*ndst+b2) -> out
// ---------------------------------------------------------------------------

__global__ __launch_bounds__(256) void k_zero(u32* __restrict__ a, u32* __restrict__ b, int n) {
    int i = blockIdx.x * 256 + threadIdx.x;
    if (i < n) { a[i] = 0u; b[i] = 0u; }
}

__global__ __launch_bounds__(256) void k_deg(const int* __restrict__ src, const int* __restrict__ dst,
                                             u32* __restrict__ dout, u32* __restrict__ din, int e) {
    int i = blockIdx.x * 256 + threadIdx.x;
    if (i < e) {
        atomicAdd(&dout[src[i]], 1u);
        atomicAdd(&din[dst[i]], 1u);
    }
}

__global__ __launch_bounds__(256) void k_norm(const u32* __restrict__ dout, const u32* __restrict__ din,
                                              float* __restrict__ nsrc, float* __restrict__ ndst, int n) {
    int i = blockIdx.x * 256 + threadIdx.x;
    if (i < n) {
        nsrc[i] = rsqrtf(fmaxf((float)dout[i], 1.0f));
        ndst[i] = rsqrtf(fmaxf((float)din[i], 1.0f));
    }
}

// Per-1024-chunk exclusive scan of deg_in; chunk totals to bsums.
__global__ __launch_bounds__(1024) void k_scan_block(const u32* __restrict__ deg, int* __restrict__ out,
                                                     u32* __restrict__ bsums, int n) {
    __shared__ u32 tmp[1024];
    int tid = threadIdx.x;
    int g = blockIdx.x * 1024 + tid;
    u32 v = (g < n) ? deg[g] : 0u;
    tmp[tid] = v;
    __syncthreads();
    for (int off = 1; off < 1024; off <<= 1) {
        u32 a = (tid >= off) ? tmp[tid - off] : 0u;
        __syncthreads();
        tmp[tid] += a;
        __syncthreads();
    }
    if (g < n) out[g] = (int)(tmp[tid] - v);
    if (tid == 1023) bsums[blockIdx.x] = tmp[1023];
}

// One wave scans the (<=64) chunk totals to exclusive offsets; writes total E.
__global__ __launch_bounds__(64) void k_scan_bsums(u32* __restrict__ bsums, int nb,
                                                   int* __restrict__ row_off, int n) {
    int lane = threadIdx.x;
    u32 v = (lane < nb) ? bsums[lane] : 0u;
    u32 s = v;
    for (int off = 1; off < 64; off <<= 1) {
        u32 o = __shfl_up(s, off, 64);
        if (lane >= off) s += o;
    }
    if (lane < nb) bsums[lane] = s - v;
    if (lane == 63) row_off[n] = (int)s;
}

__global__ __launch_bounds__(256) void k_scan_add(int* __restrict__ row_off, int* __restrict__ cursor,
                                                  const u32* __restrict__ bsums, int n) {
    int i = blockIdx.x * 256 + threadIdx.x;
    if (i < n) {
        int v = row_off[i] + (int)bsums[i >> 10];
        row_off[i] = v;
        cursor[i] = v;
    }
}

__global__ __launch_bounds__(256) void k_fill(const int* __restrict__ src, const int* __restrict__ dst,
                                              int* __restrict__ cursor, int* __restrict__ csr, int e) {
    int i = blockIdx.x * 256 + threadIdx.x;
    if (i < e) {
        int d = dst[i];
        int pos = atomicAdd(&cursor[d], 1);
        csr[pos] = src[i];
    }
}

// GEMM1: h[n,128] = (x[n,256] @ W1[256,128]) * nsrc[row]
// Block: 64 rows x 128 cols, 256 threads, each 8 rows x 4 cols. BK=32.
__global__ __launch_bounds__(256) void k_gemm1(const float* __restrict__ x, const float* __restrict__ W,
                                               const float* __restrict__ nsrc, float* __restrict__ h, int n) {
    __shared__ float xs[64][32];   // dense: f4 stores conflict-free; reads broadcast
    __shared__ float ws[32][128];  // f4 reads across 32 lanes are dense 512B -> conflict-free
    const int t = threadIdx.x;
    const int tcol = t & 31;   // 32 col-groups * 4 cols
    const int trow = t >> 5;   // 8 row-groups * 8 rows
    const int row0 = blockIdx.x * 64;

    float acc[8][4];
#pragma unroll
    for (int i = 0; i < 8; i++)
#pragma unroll
        for (int j = 0; j < 4; j++) acc[i][j] = 0.f;

    for (int k0 = 0; k0 < 256; k0 += 32) {
#pragma unroll
        for (int l = 0; l < 2; l++) {  // 512 float4s of xs
            int f = t + l * 256;
            int r = f >> 3, c4 = f & 7;
            int gr = row0 + r;
            float4 v = make_float4(0.f, 0.f, 0.f, 0.f);
            if (gr < n) v = *(const float4*)&x[(size_t)gr * 256 + k0 + c4 * 4];
            *(float4*)&xs[r][c4 * 4] = v;
        }
#pragma unroll
        for (int l = 0; l < 4; l++) {  // 1024 float4s of ws
            int f = t + l * 256;
            int r = f >> 5, c4 = f & 31;
            *(float4*)&ws[r][c4 * 4] = *(const float4*)&W[(size_t)(k0 + r) * 128 + c4 * 4];
        }
        __syncthreads();
#pragma unroll 8
        for (int kk = 0; kk < 32; kk++) {
            float4 wv = *(const float4*)&ws[kk][tcol * 4];
#pragma unroll
            for (int i = 0; i < 8; i++) {
                float xv = xs[trow * 8 + i][kk];
                acc[i][0] = fmaf(xv, wv.x, acc[i][0]);
                acc[i][1] = fmaf(xv, wv.y, acc[i][1]);
                acc[i][2] = fmaf(xv, wv.z, acc[i][2]);
                acc[i][3] = fmaf(xv, wv.w, acc[i][3]);
            }
        }
        __syncthreads();
    }
#pragma unroll
    for (int i = 0; i < 8; i++) {
        int gr = row0 + trow * 8 + i;
        if (gr < n) {
            float s = nsrc[gr];
            float4 o = make_float4(acc[i][0] * s, acc[i][1] * s, acc[i][2] * s, acc[i][3] * s);
            *(float4*)&h[(size_t)gr * 128 + tcol * 4] = o;
        }
    }
}

// agg1: one wave per dst node, lane handles cols (2*lane, 2*lane+1).
// out1s = relu(sum_{e in CSR[node]} h[src_e] * ndst + b1) * nsrc
__global__ __launch_bounds__(256) void k_agg1(const float* __restrict__ h, const int* __restrict__ row_off,
                                              const int* __restrict__ csr, const float* __restrict__ ndst,
                                              const float* __restrict__ nsrc, const float* __restrict__ b1,
                                              float* __restrict__ out1s, int n) {
    int wave = (blockIdx.x * 256 + threadIdx.x) >> 6;
    int lane = threadIdx.x & 63;
    if (wave >= n) return;
    int s = row_off[wave], epos = row_off[wave + 1];
    const int c = lane * 2;
    float a0 = 0.f, a1 = 0.f;
    for (int i = s; i < epos; ++i) {
        int src = csr[i];
        float2 v = *(const float2*)&h[(size_t)src * 128 + c];
        a0 += v.x;
        a1 += v.y;
    }
    float nd = ndst[wave], ns = nsrc[wave];
    float o0 = fmaxf(fmaf(a0, nd, b1[c]), 0.f) * ns;
    float o1 = fmaxf(fmaf(a1, nd, b1[c + 1]), 0.f) * ns;
    *(float2*)&out1s[(size_t)wave * 128 + c] = make_float2(o0, o1);
}

// GEMM2: h2[n,40] = out1s[n,128] @ W2[128,40]
// Block: 64 rows x 40 cols, 256 threads, each 2 rows x 5 cols. BK=32.
__global__ __launch_bounds__(256) void k_gemm2(const float* __restrict__ x, const float* __restrict__ W,
                                               float* __restrict__ h2, int n) {
    __shared__ float xs[64][33];  // +1 pad: reads xs[r][kk] hit distinct banks
    __shared__ float ws[32][40];
    const int t = threadIdx.x;
    const int tcol = t & 7;   // 8 col-groups * 5 cols
    const int trow = t >> 3;  // 32 row-groups * 2 rows
    const int row0 = blockIdx.x * 64;

    float acc[2][5];
#pragma unroll
    for (int i = 0; i < 2; i++)
#pragma unroll
        for (int j = 0; j < 5; j++) acc[i][j] = 0.f;

    for (int k0 = 0; k0 < 128; k0 += 32) {
#pragma unroll
        for (int l = 0; l < 2; l++) {
            int f = t + l * 256;
            int r = f >> 3, c4 = f & 7;
            int gr = row0 + r;
            float4 v = make_float4(0.f, 0.f, 0.f, 0.f);
            if (gr < n) v = *(const float4*)&x[(size_t)gr * 128 + k0 + c4 * 4];
            xs[r][c4 * 4 + 0] = v.x;
            xs[r][c4 * 4 + 1] = v.y;
            xs[r][c4 * 4 + 2] = v.z;
            xs[r][c4 * 4 + 3] = v.w;
        }
#pragma unroll
        for (int l = t; l < 1280; l += 256) {
            int r = l / 40, c = l % 40;
            ws[r][c] = W[(size_t)(k0 + r) * 40 + c];
        }
        __syncthreads();
#pragma unroll 4
        for (int kk = 0; kk < 32; kk++) {
            float w0 = ws[kk][tcol * 5 + 0];
            float w1 = ws[kk][tcol * 5 + 1];
            float w2 = ws[kk][tcol * 5 + 2];
            float w3 = ws[kk][tcol * 5 + 3];
            float w4 = ws[kk][tcol * 5 + 4];
#pragma unroll
            for (int i = 0; i < 2; i++) {
                float xv = xs[trow * 2 + i][kk];
                acc[i][0] = fmaf(xv, w0, acc[i][0]);
                acc[i][1] = fmaf(xv, w1, acc[i][1]);
                acc[i][2] = fmaf(xv, w2, acc[i][2]);
                acc[i][3] = fmaf(xv, w3, acc[i][3]);
                acc[i][4] = fmaf(xv, w4, acc[i][4]);
            }
        }
        __syncthreads();
    }
#pragma unroll
    for (int i = 0; i < 2; i++) {
        int gr = row0 + trow * 2 + i;
        if (gr < n) {
#pragma unroll
            for (int j = 0; j < 5; j++) h2[(size_t)gr * 40 + tcol * 5 + j] = acc[i][j];
        }
    }
}

// agg2: one wave per dst node, lanes 0..39 each own a column.
// out = sum h2[src_e] * ndst + b2
__global__ __launch_bounds__(256) void k_agg2(const float* __restrict__ h2, const int* __restrict__ row_off,
                                              const int* __restrict__ csr, const float* __restrict__ ndst,
                                              const float* __restrict__ b2, float* __restrict__ out, int n) {
    int wave = (blockIdx.x * 256 + threadIdx.x) >> 6;
    int lane = threadIdx.x & 63;
    if (wave >= n) return;
    int s = row_off[wave], epos = row_off[wave + 1];
    float acc = 0.f;
    if (lane < 40) {
        for (int i = s; i < epos; ++i) {
            int src = csr[i];
            acc += h2[(size_t)src * 40 + lane];
        }
        out[(size_t)wave * 40 + lane] = fmaf(acc, ndst[wave], b2[lane]);
    }
}

static inline char* align_up(char* p, size_t a) {
    return (char*)(((uintptr_t)p + (a - 1)) & ~(uintptr_t)(a - 1));
}

extern "C" void kernel_launch(void* const* d_in, const int* in_sizes, int n_in,
                              void* d_out, int out_size, void* d_ws, size_t ws_size,
                              hipStream_t stream) {
    const float* x  = (const float*)d_in[0];
    const float* W1 = (const float*)d_in[1];
    const float* b1 = (const float*)d_in[2];
    const float* W2 = (const float*)d_in[3];
    const float* b2 = (const float*)d_in[4];
    const int* esrc = (const int*)d_in[5];
    const int* edst = (const int*)d_in[6];
    float* out = (float*)d_out;

    const int n = in_sizes[0] / 256;  // 50000
    const int e = in_sizes[5];        // 800000
    const int nb = (n + 1023) / 1024;

    char* p = (char*)d_ws;
    u32* deg_out = (u32*)p;            p = align_up(p + (size_t)n * 4, 256);
    u32* deg_in  = (u32*)p;            p = align_up(p + (size_t)n * 4, 256);
    float* nsrc  = (float*)p;          p = align_up(p + (size_t)n * 4, 256);
    float* ndst  = (float*)p;          p = align_up(p + (size_t)n * 4, 256);
    int* row_off = (int*)p;            p = align_up(p + (size_t)(n + 1) * 4, 256);
    int* cursor  = (int*)p;            p = align_up(p + (size_t)n * 4, 256);
    u32* bsums   = (u32*)p;            p = align_up(p + 64 * 4, 256);
    int* csr     = (int*)p;            p = align_up(p + (size_t)e * 4, 256);
    float* h     = (float*)p;          p = align_up(p + (size_t)n * 128 * 4, 256);
    float* out1s = (float*)p;          p = align_up(p + (size_t)n * 128 * 4, 256);
    float* h2    = h;  // reuse: h dead after agg1

    const int eb = (e + 255) / 256;
    const int nb256 = (n + 255) / 256;

    k_zero<<<nb256, 256, 0, stream>>>(deg_out, deg_in, n);
    k_deg<<<eb, 256, 0, stream>>>(esrc, edst, deg_out, deg_in, e);
    k_norm<<<nb256, 256, 0, stream>>>(deg_out, deg_in, nsrc, ndst, n);
    k_scan_block<<<nb, 1024, 0, stream>>>(deg_in, row_off, bsums, n);
    k_scan_bsums<<<1, 64, 0, stream>>>(bsums, nb, row_off, n);
    k_scan_add<<<nb256, 256, 0, stream>>>(row_off, cursor, bsums, n);
    k_fill<<<eb, 256, 0, stream>>>(esrc, edst, cursor, csr, e);

    k_gemm1<<<(n + 63) / 64, 256, 0, stream>>>(x, W1, nsrc, h, n);
    k_agg1<<<(n + 3) / 4, 256, 0, stream>>>(h, row_off, csr, ndst, nsrc, b1, out1s, n);
    k_gemm2<<<(n + 63) / 64, 256, 0, stream>>>(out1s, W2, h2, n);
    k_agg2<<<(n + 3) / 4, 256, 0, stream>>>(h2, row_off, csr, ndst, b2, out, n);
}

// Round 2
// 294.549 us; speedup vs baseline: 1.2662x; 1.2662x over previous
//
#include <hip/hip_runtime.h>
#include <cstdint>
#include <cstddef>

typedef unsigned int u32;

// ---------------------------------------------------------------------------
// GCN 2-layer forward, pull-based aggregation via CSR-by-dst built on device.
//   deg/norms -> CSR(dst) -> h=(x@W1)*nsrc -> agg1(relu(.*ndst+b1)*nsrc)
//   -> h2=out1s@W2 -> agg2(.*ndst+b2) -> out
// R2: 8-deep gather pipelining in agg kernels (latency-bound fix),
//     gemm1 retiled to 128x128 block / 8x8 per-thread.
// ---------------------------------------------------------------------------

__global__ __launch_bounds__(256) void k_zero(u32* __restrict__ a, u32* __restrict__ b, int n) {
    int i = blockIdx.x * 256 + threadIdx.x;
    if (i < n) { a[i] = 0u; b[i] = 0u; }
}

__global__ __launch_bounds__(256) void k_deg(const int* __restrict__ src, const int* __restrict__ dst,
                                             u32* __restrict__ dout, u32* __restrict__ din, int e) {
    int i = blockIdx.x * 256 + threadIdx.x;
    if (i < e) {
        atomicAdd(&dout[src[i]], 1u);
        atomicAdd(&din[dst[i]], 1u);
    }
}

__global__ __launch_bounds__(256) void k_norm(const u32* __restrict__ dout, const u32* __restrict__ din,
                                              float* __restrict__ nsrc, float* __restrict__ ndst, int n) {
    int i = blockIdx.x * 256 + threadIdx.x;
    if (i < n) {
        nsrc[i] = rsqrtf(fmaxf((float)dout[i], 1.0f));
        ndst[i] = rsqrtf(fmaxf((float)din[i], 1.0f));
    }
}

// Per-1024-chunk exclusive scan of deg_in; chunk totals to bsums.
__global__ __launch_bounds__(1024) void k_scan_block(const u32* __restrict__ deg, int* __restrict__ out,
                                                     u32* __restrict__ bsums, int n) {
    __shared__ u32 tmp[1024];
    int tid = threadIdx.x;
    int g = blockIdx.x * 1024 + tid;
    u32 v = (g < n) ? deg[g] : 0u;
    tmp[tid] = v;
    __syncthreads();
    for (int off = 1; off < 1024; off <<= 1) {
        u32 a = (tid >= off) ? tmp[tid - off] : 0u;
        __syncthreads();
        tmp[tid] += a;
        __syncthreads();
    }
    if (g < n) out[g] = (int)(tmp[tid] - v);
    if (tid == 1023) bsums[blockIdx.x] = tmp[1023];
}

// One wave scans the (<=64) chunk totals to exclusive offsets; writes total E.
__global__ __launch_bounds__(64) void k_scan_bsums(u32* __restrict__ bsums, int nb,
                                                   int* __restrict__ row_off, int n) {
    int lane = threadIdx.x;
    u32 v = (lane < nb) ? bsums[lane] : 0u;
    u32 s = v;
    for (int off = 1; off < 64; off <<= 1) {
        u32 o = __shfl_up(s, off, 64);
        if (lane >= off) s += o;
    }
    if (lane < nb) bsums[lane] = s - v;
    if (lane == 63) row_off[n] = (int)s;
}

__global__ __launch_bounds__(256) void k_scan_add(int* __restrict__ row_off, int* __restrict__ cursor,
                                                  const u32* __restrict__ bsums, int n) {
    int i = blockIdx.x * 256 + threadIdx.x;
    if (i < n) {
        int v = row_off[i] + (int)bsums[i >> 10];
        row_off[i] = v;
        cursor[i] = v;
    }
}

__global__ __launch_bounds__(256) void k_fill(const int* __restrict__ src, const int* __restrict__ dst,
                                              int* __restrict__ cursor, int* __restrict__ csr, int e) {
    int i = blockIdx.x * 256 + threadIdx.x;
    if (i < e) {
        int d = dst[i];
        int pos = atomicAdd(&cursor[d], 1);
        csr[pos] = src[i];
    }
}

// GEMM1: h[n,128] = (x[n,256] @ W1[256,128]) * nsrc[row]
// Block: 128 rows x 128 cols, 256 threads, each 8x8. BK=32.
__global__ __launch_bounds__(256, 2) void k_gemm1(const float* __restrict__ x, const float* __restrict__ W,
                                                  const float* __restrict__ nsrc, float* __restrict__ h, int n) {
    __shared__ float xs[128][33];  // pad 33: stores (8 lanes/row-group) and broadcast reads conflict-free
    __shared__ float ws[32][128];
    const int t = threadIdx.x;
    const int tcol = t & 15;   // 16 col-groups * 8 cols
    const int trow = t >> 4;   // 16 row-groups * 8 rows
    const int row0 = blockIdx.x * 128;

    float acc[8][8];
#pragma unroll
    for (int i = 0; i < 8; i++)
#pragma unroll
        for (int j = 0; j < 8; j++) acc[i][j] = 0.f;

    for (int k0 = 0; k0 < 256; k0 += 32) {
#pragma unroll
        for (int l = 0; l < 4; l++) {  // 1024 float4s of xs
            int f = t + l * 256;
            int r = f >> 3, c4 = f & 7;
            int gr = row0 + r;
            float4 v = make_float4(0.f, 0.f, 0.f, 0.f);
            if (gr < n) v = *(const float4*)&x[(size_t)gr * 256 + k0 + c4 * 4];
            xs[r][c4 * 4 + 0] = v.x;
            xs[r][c4 * 4 + 1] = v.y;
            xs[r][c4 * 4 + 2] = v.z;
            xs[r][c4 * 4 + 3] = v.w;
        }
#pragma unroll
        for (int l = 0; l < 4; l++) {  // 1024 float4s of ws
            int f = t + l * 256;
            int r = f >> 5, c4 = f & 31;
            *(float4*)&ws[r][c4 * 4] = *(const float4*)&W[(size_t)(k0 + r) * 128 + c4 * 4];
        }
        __syncthreads();
#pragma unroll 4
        for (int kk = 0; kk < 32; kk++) {
            float4 w0 = *(const float4*)&ws[kk][tcol * 8];
            float4 w1 = *(const float4*)&ws[kk][tcol * 8 + 4];
#pragma unroll
            for (int i = 0; i < 8; i++) {
                float xv = xs[trow * 8 + i][kk];
                acc[i][0] = fmaf(xv, w0.x, acc[i][0]);
                acc[i][1] = fmaf(xv, w0.y, acc[i][1]);
                acc[i][2] = fmaf(xv, w0.z, acc[i][2]);
                acc[i][3] = fmaf(xv, w0.w, acc[i][3]);
                acc[i][4] = fmaf(xv, w1.x, acc[i][4]);
                acc[i][5] = fmaf(xv, w1.y, acc[i][5]);
                acc[i][6] = fmaf(xv, w1.z, acc[i][6]);
                acc[i][7] = fmaf(xv, w1.w, acc[i][7]);
            }
        }
        __syncthreads();
    }
#pragma unroll
    for (int i = 0; i < 8; i++) {
        int gr = row0 + trow * 8 + i;
        if (gr < n) {
            float s = nsrc[gr];
            float4 o0 = make_float4(acc[i][0] * s, acc[i][1] * s, acc[i][2] * s, acc[i][3] * s);
            float4 o1 = make_float4(acc[i][4] * s, acc[i][5] * s, acc[i][6] * s, acc[i][7] * s);
            *(float4*)&h[(size_t)gr * 128 + tcol * 8] = o0;
            *(float4*)&h[(size_t)gr * 128 + tcol * 8 + 4] = o1;
        }
    }
}

// agg1: one wave per dst node, lane handles cols (2*lane, 2*lane+1).
// out1s = relu(sum_{e in CSR[node]} h[src_e] * ndst + b1) * nsrc
// 8-deep gather pipeline: issue 8 independent row-gathers before accumulating.
__global__ __launch_bounds__(256) void k_agg1(const float* __restrict__ h, const int* __restrict__ row_off,
                                              const int* __restrict__ csr, const float* __restrict__ ndst,
                                              const float* __restrict__ nsrc, const float* __restrict__ b1,
                                              float* __restrict__ out1s, int n) {
    int wave = (blockIdx.x * 256 + threadIdx.x) >> 6;
    int lane = threadIdx.x & 63;
    if (wave >= n) return;
    int s = row_off[wave], epos = row_off[wave + 1];
    const int c = lane * 2;
    float a0 = 0.f, a1 = 0.f;
    int i = s;
    for (; i + 8 <= epos; i += 8) {
        int idx[8];
#pragma unroll
        for (int j = 0; j < 8; j++) idx[j] = csr[i + j];
        float2 v[8];
#pragma unroll
        for (int j = 0; j < 8; j++) v[j] = *(const float2*)&h[(size_t)idx[j] * 128 + c];
#pragma unroll
        for (int j = 0; j < 8; j++) { a0 += v[j].x; a1 += v[j].y; }
    }
    if (i + 4 <= epos) {
        int i0 = csr[i], i1 = csr[i + 1], i2 = csr[i + 2], i3 = csr[i + 3];
        float2 v0 = *(const float2*)&h[(size_t)i0 * 128 + c];
        float2 v1 = *(const float2*)&h[(size_t)i1 * 128 + c];
        float2 v2 = *(const float2*)&h[(size_t)i2 * 128 + c];
        float2 v3 = *(const float2*)&h[(size_t)i3 * 128 + c];
        a0 += v0.x + v1.x + v2.x + v3.x;
        a1 += v0.y + v1.y + v2.y + v3.y;
        i += 4;
    }
    if (i + 2 <= epos) {
        int i0 = csr[i], i1 = csr[i + 1];
        float2 v0 = *(const float2*)&h[(size_t)i0 * 128 + c];
        float2 v1 = *(const float2*)&h[(size_t)i1 * 128 + c];
        a0 += v0.x + v1.x;
        a1 += v0.y + v1.y;
        i += 2;
    }
    if (i < epos) {
        int i0 = csr[i];
        float2 v0 = *(const float2*)&h[(size_t)i0 * 128 + c];
        a0 += v0.x;
        a1 += v0.y;
    }
    float nd = ndst[wave], ns = nsrc[wave];
    float o0 = fmaxf(fmaf(a0, nd, b1[c]), 0.f) * ns;
    float o1 = fmaxf(fmaf(a1, nd, b1[c + 1]), 0.f) * ns;
    *(float2*)&out1s[(size_t)wave * 128 + c] = make_float2(o0, o1);
}

// GEMM2: h2[n,40] = out1s[n,128] @ W2[128,40]
__global__ __launch_bounds__(256) void k_gemm2(const float* __restrict__ x, const float* __restrict__ W,
                                               float* __restrict__ h2, int n) {
    __shared__ float xs[64][33];
    __shared__ float ws[32][40];
    const int t = threadIdx.x;
    const int tcol = t & 7;   // 8 col-groups * 5 cols
    const int trow = t >> 3;  // 32 row-groups * 2 rows
    const int row0 = blockIdx.x * 64;

    float acc[2][5];
#pragma unroll
    for (int i = 0; i < 2; i++)
#pragma unroll
        for (int j = 0; j < 5; j++) acc[i][j] = 0.f;

    for (int k0 = 0; k0 < 128; k0 += 32) {
#pragma unroll
        for (int l = 0; l < 2; l++) {
            int f = t + l * 256;
            int r = f >> 3, c4 = f & 7;
            int gr = row0 + r;
            float4 v = make_float4(0.f, 0.f, 0.f, 0.f);
            if (gr < n) v = *(const float4*)&x[(size_t)gr * 128 + k0 + c4 * 4];
            xs[r][c4 * 4 + 0] = v.x;
            xs[r][c4 * 4 + 1] = v.y;
            xs[r][c4 * 4 + 2] = v.z;
            xs[r][c4 * 4 + 3] = v.w;
        }
#pragma unroll
        for (int l = t; l < 1280; l += 256) {
            int r = l / 40, c = l % 40;
            ws[r][c] = W[(size_t)(k0 + r) * 40 + c];
        }
        __syncthreads();
#pragma unroll 4
        for (int kk = 0; kk < 32; kk++) {
            float w0 = ws[kk][tcol * 5 + 0];
            float w1 = ws[kk][tcol * 5 + 1];
            float w2 = ws[kk][tcol * 5 + 2];
            float w3 = ws[kk][tcol * 5 + 3];
            float w4 = ws[kk][tcol * 5 + 4];
#pragma unroll
            for (int i = 0; i < 2; i++) {
                float xv = xs[trow * 2 + i][kk];
                acc[i][0] = fmaf(xv, w0, acc[i][0]);
                acc[i][1] = fmaf(xv, w1, acc[i][1]);
                acc[i][2] = fmaf(xv, w2, acc[i][2]);
                acc[i][3] = fmaf(xv, w3, acc[i][3]);
                acc[i][4] = fmaf(xv, w4, acc[i][4]);
            }
        }
        __syncthreads();
    }
#pragma unroll
    for (int i = 0; i < 2; i++) {
        int gr = row0 + trow * 2 + i;
        if (gr < n) {
#pragma unroll
            for (int j = 0; j < 5; j++) h2[(size_t)gr * 40 + tcol * 5 + j] = acc[i][j];
        }
    }
}

// agg2: one wave per dst node, lanes 0..39 each own a column. 8-deep pipeline.
__global__ __launch_bounds__(256) void k_agg2(const float* __restrict__ h2, const int* __restrict__ row_off,
                                              const int* __restrict__ csr, const float* __restrict__ ndst,
                                              const float* __restrict__ b2, float* __restrict__ out, int n) {
    int wave = (blockIdx.x * 256 + threadIdx.x) >> 6;
    int lane = threadIdx.x & 63;
    if (wave >= n) return;
    int s = row_off[wave], epos = row_off[wave + 1];
    if (lane >= 40) return;
    float acc = 0.f;
    int i = s;
    for (; i + 8 <= epos; i += 8) {
        int idx[8];
#pragma unroll
        for (int j = 0; j < 8; j++) idx[j] = csr[i + j];
        float v[8];
#pragma unroll
        for (int j = 0; j < 8; j++) v[j] = h2[(size_t)idx[j] * 40 + lane];
#pragma unroll
        for (int j = 0; j < 8; j++) acc += v[j];
    }
    if (i + 4 <= epos) {
        int i0 = csr[i], i1 = csr[i + 1], i2 = csr[i + 2], i3 = csr[i + 3];
        float v0 = h2[(size_t)i0 * 40 + lane];
        float v1 = h2[(size_t)i1 * 40 + lane];
        float v2 = h2[(size_t)i2 * 40 + lane];
        float v3 = h2[(size_t)i3 * 40 + lane];
        acc += v0 + v1 + v2 + v3;
        i += 4;
    }
    if (i + 2 <= epos) {
        int i0 = csr[i], i1 = csr[i + 1];
        float v0 = h2[(size_t)i0 * 40 + lane];
        float v1 = h2[(size_t)i1 * 40 + lane];
        acc += v0 + v1;
        i += 2;
    }
    if (i < epos) {
        acc += h2[(size_t)csr[i] * 40 + lane];
    }
    out[(size_t)wave * 40 + lane] = fmaf(acc, ndst[wave], b2[lane]);
}

static inline char* align_up(char* p, size_t a) {
    return (char*)(((uintptr_t)p + (a - 1)) & ~(uintptr_t)(a - 1));
}

extern "C" void kernel_launch(void* const* d_in, const int* in_sizes, int n_in,
                              void* d_out, int out_size, void* d_ws, size_t ws_size,
                              hipStream_t stream) {
    const float* x  = (const float*)d_in[0];
    const float* W1 = (const float*)d_in[1];
    const float* b1 = (const float*)d_in[2];
    const float* W2 = (const float*)d_in[3];
    const float* b2 = (const float*)d_in[4];
    const int* esrc = (const int*)d_in[5];
    const int* edst = (const int*)d_in[6];
    float* out = (float*)d_out;

    const int n = in_sizes[0] / 256;  // 50000
    const int e = in_sizes[5];        // 800000
    const int nb = (n + 1023) / 1024;

    char* p = (char*)d_ws;
    u32* deg_out = (u32*)p;            p = align_up(p + (size_t)n * 4, 256);
    u32* deg_in  = (u32*)p;            p = align_up(p + (size_t)n * 4, 256);
    float* nsrc  = (float*)p;          p = align_up(p + (size_t)n * 4, 256);
    float* ndst  = (float*)p;          p = align_up(p + (size_t)n * 4, 256);
    int* row_off = (int*)p;            p = align_up(p + (size_t)(n + 1) * 4, 256);
    int* cursor  = (int*)p;            p = align_up(p + (size_t)n * 4, 256);
    u32* bsums   = (u32*)p;            p = align_up(p + 64 * 4, 256);
    int* csr     = (int*)p;            p = align_up(p + (size_t)e * 4, 256);
    float* h     = (float*)p;          p = align_up(p + (size_t)n * 128 * 4, 256);
    float* out1s = (float*)p;          p = align_up(p + (size_t)n * 128 * 4, 256);
    float* h2    = h;  // reuse: h dead after agg1

    const int eb = (e + 255) / 256;
    const int nb256 = (n + 255) / 256;

    k_zero<<<nb256, 256, 0, stream>>>(deg_out, deg_in, n);
    k_deg<<<eb, 256, 0, stream>>>(esrc, edst, deg_out, deg_in, e);
    k_norm<<<nb256, 256, 0, stream>>>(deg_out, deg_in, nsrc, ndst, n);
    k_scan_block<<<nb, 1024, 0, stream>>>(deg_in, row_off, bsums, n);
    k_scan_bsums<<<1, 64, 0, stream>>>(bsums, nb, row_off, n);
    k_scan_add<<<nb256, 256, 0, stream>>>(row_off, cursor, bsums, n);
    k_fill<<<eb, 256, 0, stream>>>(esrc, edst, cursor, csr, e);

    k_gemm1<<<(n + 127) / 128, 256, 0, stream>>>(x, W1, nsrc, h, n);
    k_agg1<<<(n + 3) / 4, 256, 0, stream>>>(h, row_off, csr, ndst, nsrc, b1, out1s, n);
    k_gemm2<<<(n + 63) / 64, 256, 0, stream>>>(out1s, W2, h2, n);
    k_agg2<<<(n + 3) / 4, 256, 0, stream>>>(h2, row_off, csr, ndst, b2, out, n);
}

// Round 3
// 289.370 us; speedup vs baseline: 1.2888x; 1.0179x over previous
//
#include <hip/hip_runtime.h>
#include <cstdint>
#include <cstddef>

typedef unsigned int u32;

// ---------------------------------------------------------------------------
// GCN 2-layer forward, pull-based aggregation via CSR-by-dst built on device.
//   deg/norms -> CSR(dst) -> h=(x@W1)*nsrc -> agg1(relu(.*ndst+b1)*nsrc)
//   -> h2=out1s@W2 -> agg2(.*ndst+b2) -> out
// R3: gemm1 retiled 64x128 (grid 782 = 3/CU, launch_bounds(256,4)),
//     all-float4 LDS (dense b128 stores, b128 k-grouped reads).
// ---------------------------------------------------------------------------

__global__ __launch_bounds__(256) void k_zero(u32* __restrict__ a, u32* __restrict__ b, int n) {
    int i = blockIdx.x * 256 + threadIdx.x;
    if (i < n) { a[i] = 0u; b[i] = 0u; }
}

__global__ __launch_bounds__(256) void k_deg(const int* __restrict__ src, const int* __restrict__ dst,
                                             u32* __restrict__ dout, u32* __restrict__ din, int e) {
    int i = blockIdx.x * 256 + threadIdx.x;
    if (i < e) {
        atomicAdd(&dout[src[i]], 1u);
        atomicAdd(&din[dst[i]], 1u);
    }
}

__global__ __launch_bounds__(256) void k_norm(const u32* __restrict__ dout, const u32* __restrict__ din,
                                              float* __restrict__ nsrc, float* __restrict__ ndst, int n) {
    int i = blockIdx.x * 256 + threadIdx.x;
    if (i < n) {
        nsrc[i] = rsqrtf(fmaxf((float)dout[i], 1.0f));
        ndst[i] = rsqrtf(fmaxf((float)din[i], 1.0f));
    }
}

// Per-1024-chunk exclusive scan of deg_in; chunk totals to bsums.
__global__ __launch_bounds__(1024) void k_scan_block(const u32* __restrict__ deg, int* __restrict__ out,
                                                     u32* __restrict__ bsums, int n) {
    __shared__ u32 tmp[1024];
    int tid = threadIdx.x;
    int g = blockIdx.x * 1024 + tid;
    u32 v = (g < n) ? deg[g] : 0u;
    tmp[tid] = v;
    __syncthreads();
    for (int off = 1; off < 1024; off <<= 1) {
        u32 a = (tid >= off) ? tmp[tid - off] : 0u;
        __syncthreads();
        tmp[tid] += a;
        __syncthreads();
    }
    if (g < n) out[g] = (int)(tmp[tid] - v);
    if (tid == 1023) bsums[blockIdx.x] = tmp[1023];
}

// One wave scans the (<=64) chunk totals to exclusive offsets; writes total E.
__global__ __launch_bounds__(64) void k_scan_bsums(u32* __restrict__ bsums, int nb,
                                                   int* __restrict__ row_off, int n) {
    int lane = threadIdx.x;
    u32 v = (lane < nb) ? bsums[lane] : 0u;
    u32 s = v;
    for (int off = 1; off < 64; off <<= 1) {
        u32 o = __shfl_up(s, off, 64);
        if (lane >= off) s += o;
    }
    if (lane < nb) bsums[lane] = s - v;
    if (lane == 63) row_off[n] = (int)s;
}

__global__ __launch_bounds__(256) void k_scan_add(int* __restrict__ row_off, int* __restrict__ cursor,
                                                  const u32* __restrict__ bsums, int n) {
    int i = blockIdx.x * 256 + threadIdx.x;
    if (i < n) {
        int v = row_off[i] + (int)bsums[i >> 10];
        row_off[i] = v;
        cursor[i] = v;
    }
}

__global__ __launch_bounds__(256) void k_fill(const int* __restrict__ src, const int* __restrict__ dst,
                                              int* __restrict__ cursor, int* __restrict__ csr, int e) {
    int i = blockIdx.x * 256 + threadIdx.x;
    if (i < e) {
        int d = dst[i];
        int pos = atomicAdd(&cursor[d], 1);
        csr[pos] = src[i];
    }
}

// GEMM1: h[n,128] = (x[n,256] @ W1[256,128]) * nsrc[row]
// Block: 64 rows x 128 cols, 256 threads, each 8 rows x 4 cols. BK=32.
// All LDS traffic is b128 and conflict-free:
//   xs[64][32] float4 stores are word=4*lane dense; reads are 2-addr broadcast.
//   ws float4 stores dense; reads 32-lane x 16B = 512B dense.
__global__ __launch_bounds__(256, 4) void k_gemm1(const float* __restrict__ x, const float* __restrict__ W,
                                                  const float* __restrict__ nsrc, float* __restrict__ h, int n) {
    __shared__ float xs[64][32];
    __shared__ float ws[32][128];
    const int t = threadIdx.x;
    const int tcol = t & 31;   // 32 col-groups * 4 cols
    const int trow = t >> 5;   // 8 row-groups * 8 rows
    const int row0 = blockIdx.x * 64;

    float acc[8][4];
#pragma unroll
    for (int i = 0; i < 8; i++)
#pragma unroll
        for (int j = 0; j < 4; j++) acc[i][j] = 0.f;

    for (int k0 = 0; k0 < 256; k0 += 32) {
#pragma unroll
        for (int l = 0; l < 2; l++) {  // 512 float4s of xs
            int f = t + l * 256;
            int r = f >> 3, c4 = f & 7;
            int gr = row0 + r;
            float4 v = make_float4(0.f, 0.f, 0.f, 0.f);
            if (gr < n) v = *(const float4*)&x[(size_t)gr * 256 + k0 + c4 * 4];
            *(float4*)&xs[r][c4 * 4] = v;
        }
#pragma unroll
        for (int l = 0; l < 4; l++) {  // 1024 float4s of ws
            int f = t + l * 256;
            int r = f >> 5, c4 = f & 31;
            *(float4*)&ws[r][c4 * 4] = *(const float4*)&W[(size_t)(k0 + r) * 128 + c4 * 4];
        }
        __syncthreads();
#pragma unroll
        for (int kk = 0; kk < 32; kk += 4) {
            float4 xv[8];
#pragma unroll
            for (int i = 0; i < 8; i++) xv[i] = *(const float4*)&xs[trow * 8 + i][kk];
            float4 wv[4];
#pragma unroll
            for (int j = 0; j < 4; j++) wv[j] = *(const float4*)&ws[kk + j][tcol * 4];
#pragma unroll
            for (int i = 0; i < 8; i++) {
                acc[i][0] = fmaf(xv[i].x, wv[0].x, acc[i][0]);
                acc[i][1] = fmaf(xv[i].x, wv[0].y, acc[i][1]);
                acc[i][2] = fmaf(xv[i].x, wv[0].z, acc[i][2]);
                acc[i][3] = fmaf(xv[i].x, wv[0].w, acc[i][3]);
                acc[i][0] = fmaf(xv[i].y, wv[1].x, acc[i][0]);
                acc[i][1] = fmaf(xv[i].y, wv[1].y, acc[i][1]);
                acc[i][2] = fmaf(xv[i].y, wv[1].z, acc[i][2]);
                acc[i][3] = fmaf(xv[i].y, wv[1].w, acc[i][3]);
                acc[i][0] = fmaf(xv[i].z, wv[2].x, acc[i][0]);
                acc[i][1] = fmaf(xv[i].z, wv[2].y, acc[i][1]);
                acc[i][2] = fmaf(xv[i].z, wv[2].z, acc[i][2]);
                acc[i][3] = fmaf(xv[i].z, wv[2].w, acc[i][3]);
                acc[i][0] = fmaf(xv[i].w, wv[3].x, acc[i][0]);
                acc[i][1] = fmaf(xv[i].w, wv[3].y, acc[i][1]);
                acc[i][2] = fmaf(xv[i].w, wv[3].z, acc[i][2]);
                acc[i][3] = fmaf(xv[i].w, wv[3].w, acc[i][3]);
            }
        }
        __syncthreads();
    }
#pragma unroll
    for (int i = 0; i < 8; i++) {
        int gr = row0 + trow * 8 + i;
        if (gr < n) {
            float s = nsrc[gr];
            float4 o = make_float4(acc[i][0] * s, acc[i][1] * s, acc[i][2] * s, acc[i][3] * s);
            *(float4*)&h[(size_t)gr * 128 + tcol * 4] = o;
        }
    }
}

// agg1: one wave per dst node, lane handles cols (2*lane, 2*lane+1).
// out1s = relu(sum_{e in CSR[node]} h[src_e] * ndst + b1) * nsrc
// 8-deep gather pipeline: issue 8 independent row-gathers before accumulating.
__global__ __launch_bounds__(256) void k_agg1(const float* __restrict__ h, const int* __restrict__ row_off,
                                              const int* __restrict__ csr, const float* __restrict__ ndst,
                                              const float* __restrict__ nsrc, const float* __restrict__ b1,
                                              float* __restrict__ out1s, int n) {
    int wave = (blockIdx.x * 256 + threadIdx.x) >> 6;
    int lane = threadIdx.x & 63;
    if (wave >= n) return;
    int s = row_off[wave], epos = row_off[wave + 1];
    const int c = lane * 2;
    float a0 = 0.f, a1 = 0.f;
    int i = s;
    for (; i + 8 <= epos; i += 8) {
        int idx[8];
#pragma unroll
        for (int j = 0; j < 8; j++) idx[j] = csr[i + j];
        float2 v[8];
#pragma unroll
        for (int j = 0; j < 8; j++) v[j] = *(const float2*)&h[(size_t)idx[j] * 128 + c];
#pragma unroll
        for (int j = 0; j < 8; j++) { a0 += v[j].x; a1 += v[j].y; }
    }
    if (i + 4 <= epos) {
        int i0 = csr[i], i1 = csr[i + 1], i2 = csr[i + 2], i3 = csr[i + 3];
        float2 v0 = *(const float2*)&h[(size_t)i0 * 128 + c];
        float2 v1 = *(const float2*)&h[(size_t)i1 * 128 + c];
        float2 v2 = *(const float2*)&h[(size_t)i2 * 128 + c];
        float2 v3 = *(const float2*)&h[(size_t)i3 * 128 + c];
        a0 += v0.x + v1.x + v2.x + v3.x;
        a1 += v0.y + v1.y + v2.y + v3.y;
        i += 4;
    }
    if (i + 2 <= epos) {
        int i0 = csr[i], i1 = csr[i + 1];
        float2 v0 = *(const float2*)&h[(size_t)i0 * 128 + c];
        float2 v1 = *(const float2*)&h[(size_t)i1 * 128 + c];
        a0 += v0.x + v1.x;
        a1 += v0.y + v1.y;
        i += 2;
    }
    if (i < epos) {
        int i0 = csr[i];
        float2 v0 = *(const float2*)&h[(size_t)i0 * 128 + c];
        a0 += v0.x;
        a1 += v0.y;
    }
    float nd = ndst[wave], ns = nsrc[wave];
    float o0 = fmaxf(fmaf(a0, nd, b1[c]), 0.f) * ns;
    float o1 = fmaxf(fmaf(a1, nd, b1[c + 1]), 0.f) * ns;
    *(float2*)&out1s[(size_t)wave * 128 + c] = make_float2(o0, o1);
}

// GEMM2: h2[n,40] = out1s[n,128] @ W2[128,40]
__global__ __launch_bounds__(256) void k_gemm2(const float* __restrict__ x, const float* __restrict__ W,
                                               float* __restrict__ h2, int n) {
    __shared__ float xs[64][33];
    __shared__ float ws[32][40];
    const int t = threadIdx.x;
    const int tcol = t & 7;   // 8 col-groups * 5 cols
    const int trow = t >> 3;  // 32 row-groups * 2 rows
    const int row0 = blockIdx.x * 64;

    float acc[2][5];
#pragma unroll
    for (int i = 0; i < 2; i++)
#pragma unroll
        for (int j = 0; j < 5; j++) acc[i][j] = 0.f;

    for (int k0 = 0; k0 < 128; k0 += 32) {
#pragma unroll
        for (int l = 0; l < 2; l++) {
            int f = t + l * 256;
            int r = f >> 3, c4 = f & 7;
            int gr = row0 + r;
            float4 v = make_float4(0.f, 0.f, 0.f, 0.f);
            if (gr < n) v = *(const float4*)&x[(size_t)gr * 128 + k0 + c4 * 4];
            xs[r][c4 * 4 + 0] = v.x;
            xs[r][c4 * 4 + 1] = v.y;
            xs[r][c4 * 4 + 2] = v.z;
            xs[r][c4 * 4 + 3] = v.w;
        }
#pragma unroll
        for (int l = t; l < 1280; l += 256) {
            int r = l / 40, c = l % 40;
            ws[r][c] = W[(size_t)(k0 + r) * 40 + c];
        }
        __syncthreads();
#pragma unroll 4
        for (int kk = 0; kk < 32; kk++) {
            float w0 = ws[kk][tcol * 5 + 0];
            float w1 = ws[kk][tcol * 5 + 1];
            float w2 = ws[kk][tcol * 5 + 2];
            float w3 = ws[kk][tcol * 5 + 3];
            float w4 = ws[kk][tcol * 5 + 4];
#pragma unroll
            for (int i = 0; i < 2; i++) {
                float xv = xs[trow * 2 + i][kk];
                acc[i][0] = fmaf(xv, w0, acc[i][0]);
                acc[i][1] = fmaf(xv, w1, acc[i][1]);
                acc[i][2] = fmaf(xv, w2, acc[i][2]);
                acc[i][3] = fmaf(xv, w3, acc[i][3]);
                acc[i][4] = fmaf(xv, w4, acc[i][4]);
            }
        }
        __syncthreads();
    }
#pragma unroll
    for (int i = 0; i < 2; i++) {
        int gr = row0 + trow * 2 + i;
        if (gr < n) {
#pragma unroll
            for (int j = 0; j < 5; j++) h2[(size_t)gr * 40 + tcol * 5 + j] = acc[i][j];
        }
    }
}

// agg2: one wave per dst node, lanes 0..39 each own a column. 8-deep pipeline.
__global__ __launch_bounds__(256) void k_agg2(const float* __restrict__ h2, const int* __restrict__ row_off,
                                              const int* __restrict__ csr, const float* __restrict__ ndst,
                                              const float* __restrict__ b2, float* __restrict__ out, int n) {
    int wave = (blockIdx.x * 256 + threadIdx.x) >> 6;
    int lane = threadIdx.x & 63;
    if (wave >= n) return;
    int s = row_off[wave], epos = row_off[wave + 1];
    if (lane >= 40) return;
    float acc = 0.f;
    int i = s;
    for (; i + 8 <= epos; i += 8) {
        int idx[8];
#pragma unroll
        for (int j = 0; j < 8; j++) idx[j] = csr[i + j];
        float v[8];
#pragma unroll
        for (int j = 0; j < 8; j++) v[j] = h2[(size_t)idx[j] * 40 + lane];
#pragma unroll
        for (int j = 0; j < 8; j++) acc += v[j];
    }
    if (i + 4 <= epos) {
        int i0 = csr[i], i1 = csr[i + 1], i2 = csr[i + 2], i3 = csr[i + 3];
        float v0 = h2[(size_t)i0 * 40 + lane];
        float v1 = h2[(size_t)i1 * 40 + lane];
        float v2 = h2[(size_t)i2 * 40 + lane];
        float v3 = h2[(size_t)i3 * 40 + lane];
        acc += v0 + v1 + v2 + v3;
        i += 4;
    }
    if (i + 2 <= epos) {
        int i0 = csr[i], i1 = csr[i + 1];
        float v0 = h2[(size_t)i0 * 40 + lane];
        float v1 = h2[(size_t)i1 * 40 + lane];
        acc += v0 + v1;
        i += 2;
    }
    if (i < epos) {
        acc += h2[(size_t)csr[i] * 40 + lane];
    }
    out[(size_t)wave * 40 + lane] = fmaf(acc, ndst[wave], b2[lane]);
}

static inline char* align_up(char* p, size_t a) {
    return (char*)(((uintptr_t)p + (a - 1)) & ~(uintptr_t)(a - 1));
}

extern "C" void kernel_launch(void* const* d_in, const int* in_sizes, int n_in,
                              void* d_out, int out_size, void* d_ws, size_t ws_size,
                              hipStream_t stream) {
    const float* x  = (const float*)d_in[0];
    const float* W1 = (const float*)d_in[1];
    const float* b1 = (const float*)d_in[2];
    const float* W2 = (const float*)d_in[3];
    const float* b2 = (const float*)d_in[4];
    const int* esrc = (const int*)d_in[5];
    const int* edst = (const int*)d_in[6];
    float* out = (float*)d_out;

    const int n = in_sizes[0] / 256;  // 50000
    const int e = in_sizes[5];        // 800000
    const int nb = (n + 1023) / 1024;

    char* p = (char*)d_ws;
    u32* deg_out = (u32*)p;            p = align_up(p + (size_t)n * 4, 256);
    u32* deg_in  = (u32*)p;            p = align_up(p + (size_t)n * 4, 256);
    float* nsrc  = (float*)p;          p = align_up(p + (size_t)n * 4, 256);
    float* ndst  = (float*)p;          p = align_up(p + (size_t)n * 4, 256);
    int* row_off = (int*)p;            p = align_up(p + (size_t)(n + 1) * 4, 256);
    int* cursor  = (int*)p;            p = align_up(p + (size_t)n * 4, 256);
    u32* bsums   = (u32*)p;            p = align_up(p + 64 * 4, 256);
    int* csr     = (int*)p;            p = align_up(p + (size_t)e * 4, 256);
    float* h     = (float*)p;          p = align_up(p + (size_t)n * 128 * 4, 256);
    float* out1s = (float*)p;          p = align_up(p + (size_t)n * 128 * 4, 256);
    float* h2    = h;  // reuse: h dead after agg1

    const int eb = (e + 255) / 256;
    const int nb256 = (n + 255) / 256;

    k_zero<<<nb256, 256, 0, stream>>>(deg_out, deg_in, n);
    k_deg<<<eb, 256, 0, stream>>>(esrc, edst, deg_out, deg_in, e);
    k_norm<<<nb256, 256, 0, stream>>>(deg_out, deg_in, nsrc, ndst, n);
    k_scan_block<<<nb, 1024, 0, stream>>>(deg_in, row_off, bsums, n);
    k_scan_bsums<<<1, 64, 0, stream>>>(bsums, nb, row_off, n);
    k_scan_add<<<nb256, 256, 0, stream>>>(row_off, cursor, bsums, n);
    k_fill<<<eb, 256, 0, stream>>>(esrc, edst, cursor, csr, e);

    k_gemm1<<<(n + 63) / 64, 256, 0, stream>>>(x, W1, nsrc, h, n);
    k_agg1<<<(n + 3) / 4, 256, 0, stream>>>(h, row_off, csr, ndst, nsrc, b1, out1s, n);
    k_gemm2<<<(n + 63) / 64, 256, 0, stream>>>(out1s, W2, h2, n);
    k_agg2<<<(n + 3) / 4, 256, 0, stream>>>(h2, row_off, csr, ndst, b2, out, n);
}